// Round 1
// baseline (412.158 us; speedup 1.0000x reference)
//
#include <hip/hip_runtime.h>

#define NE 24
#define NB 8192
#define FIN 15
#define H1 512
#define H2 512
#define H3 256
#define TS 16
#define MAXT (NB / TS + NE)  // 536 upper bound on total tiles

// ---- ws layout (int32 units) ----
#define WS_COUNT 0     // [24]  per-expert histogram
#define WS_OFF   32    // [25]  exclusive prefix (bucket offsets)
#define WS_CUR   64    // [24]  scatter cursors
#define WS_NT    96    // [1]   total tile count
#define WS_TE    128   // [MAXT] tile -> expert
#define WS_TT    1024  // [MAXT] tile -> tile-index-within-expert
#define WS_ORD   2048  // [NB]  sample indices sorted by expert

__global__ void k_zero(int* __restrict__ ws) {
  ws[threadIdx.x] = 0;  // zeroes counts/cursors/nt region [0,128)
}

__global__ void k_hist(const int* __restrict__ idx, int* __restrict__ ws) {
  int i = blockIdx.x * 256 + threadIdx.x;
  atomicAdd(&ws[WS_COUNT + idx[i]], 1);
}

__global__ void k_plan(int* __restrict__ ws) {
  __shared__ int tileoff[NE + 1];
  int t = threadIdx.x;
  if (t == 0) {
    int off = 0, toff = 0;
    for (int e = 0; e < NE; ++e) {
      ws[WS_OFF + e] = off;
      ws[WS_CUR + e] = off;
      tileoff[e] = toff;
      int c = ws[WS_COUNT + e];
      off += c;
      toff += (c + TS - 1) / TS;
    }
    ws[WS_OFF + NE] = off;
    tileoff[NE] = toff;
    ws[WS_NT] = toff;
  }
  __syncthreads();
  for (int e = 0; e < NE; ++e) {
    int base = tileoff[e];
    int nt = tileoff[e + 1] - base;
    for (int k = t; k < nt; k += 64) {
      ws[WS_TE + base + k] = e;
      ws[WS_TT + base + k] = k;
    }
  }
}

__global__ void k_scatter(const int* __restrict__ idx, int* __restrict__ ws) {
  int i = blockIdx.x * 256 + threadIdx.x;
  int e = idx[i];
  int p = atomicAdd(&ws[WS_CUR + e], 1);
  ws[WS_ORD + p] = i;
}

__global__ __launch_bounds__(256) void k_mlp(
    const float* __restrict__ features,
    const float* __restrict__ W1, const float* __restrict__ b1,
    const float* __restrict__ W2, const float* __restrict__ b2,
    const float* __restrict__ W3, const float* __restrict__ b3,
    const float* __restrict__ W4, const float* __restrict__ b4,
    const int* __restrict__ ws, float* __restrict__ out)
{
  __shared__ __align__(16) float feat[TS][16];
  __shared__ __align__(16) float bufA[TS][H1];  // h1, later reused for h3
  __shared__ __align__(16) float bufB[TS][H2];  // h2
  __shared__ int sidx[TS];

  const int t = threadIdx.x;
  const int bid = blockIdx.x;
  const int nt = ws[WS_NT];
  if (bid >= nt) return;  // uniform per-block: safe w.r.t. barriers
  const int e  = ws[WS_TE + bid];
  const int t0 = ws[WS_TT + bid];
  const int start = ws[WS_OFF + e] + t0 * TS;
  const int cnt = min(TS, ws[WS_OFF + e + 1] - start);

  if (t < TS) sidx[t] = (t < cnt) ? ws[WS_ORD + start + t] : -1;
  __syncthreads();
  {
    int s = t >> 4, f = t & 15;
    float v = 0.f;
    if (f < FIN && s < cnt) v = features[sidx[s] * FIN + f];
    feat[s][f] = v;
  }
  __syncthreads();

  // ---- layer 1: [16 x 15] @ [15 x 512] -> bufA ----
  {
    const float* w1 = W1 + e * FIN * H1;
    #pragma unroll
    for (int cc = 0; cc < 2; ++cc) {
      const int c = t + cc * 256;
      float wv[FIN];
      #pragma unroll
      for (int i = 0; i < FIN; ++i) wv[i] = w1[i * H1 + c];
      const float bb = b1[e * H1 + c];
      #pragma unroll
      for (int s = 0; s < TS; ++s) {
        float a = bb;
        #pragma unroll
        for (int i = 0; i < FIN; ++i) a = fmaf(feat[s][i], wv[i], a);
        bufA[s][c] = fmaxf(a, 0.f);
      }
    }
  }
  __syncthreads();

  // ---- layer 2: [16 x 512] @ [512 x 512] -> bufB ----
  {
    const float* w2 = W2 + e * H1 * H2;
    float acc0[TS], acc1[TS];
    #pragma unroll
    for (int s = 0; s < TS; ++s) { acc0[s] = 0.f; acc1[s] = 0.f; }
    for (int h = 0; h < H1; h += 4) {
      float wa[4], wb[4];
      #pragma unroll
      for (int j = 0; j < 4; ++j) {
        wa[j] = w2[(h + j) * H2 + t];
        wb[j] = w2[(h + j) * H2 + t + 256];
      }
      #pragma unroll
      for (int s = 0; s < TS; ++s) {
        const float4 a = *(const float4*)&bufA[s][h];  // block-uniform broadcast
        acc0[s] = fmaf(a.x, wa[0], acc0[s]);
        acc0[s] = fmaf(a.y, wa[1], acc0[s]);
        acc0[s] = fmaf(a.z, wa[2], acc0[s]);
        acc0[s] = fmaf(a.w, wa[3], acc0[s]);
        acc1[s] = fmaf(a.x, wb[0], acc1[s]);
        acc1[s] = fmaf(a.y, wb[1], acc1[s]);
        acc1[s] = fmaf(a.z, wb[2], acc1[s]);
        acc1[s] = fmaf(a.w, wb[3], acc1[s]);
      }
    }
    const float bb0 = b2[e * H2 + t];
    const float bb1 = b2[e * H2 + t + 256];
    #pragma unroll
    for (int s = 0; s < TS; ++s) {
      bufB[s][t]       = fmaxf(acc0[s] + bb0, 0.f);
      bufB[s][t + 256] = fmaxf(acc1[s] + bb1, 0.f);
    }
  }
  __syncthreads();

  // ---- layer 3: [16 x 512] @ [512 x 256] -> bufA (cols 0..255) ----
  {
    const float* w3 = W3 + e * H2 * H3;
    float acc[TS];
    #pragma unroll
    for (int s = 0; s < TS; ++s) acc[s] = 0.f;
    for (int k = 0; k < H2; k += 4) {
      float w[4];
      #pragma unroll
      for (int j = 0; j < 4; ++j) w[j] = w3[(k + j) * H3 + t];
      #pragma unroll
      for (int s = 0; s < TS; ++s) {
        const float4 a = *(const float4*)&bufB[s][k];
        acc[s] = fmaf(a.x, w[0], acc[s]);
        acc[s] = fmaf(a.y, w[1], acc[s]);
        acc[s] = fmaf(a.z, w[2], acc[s]);
        acc[s] = fmaf(a.w, w[3], acc[s]);
      }
    }
    const float bb = b3[e * H3 + t];
    #pragma unroll
    for (int s = 0; s < TS; ++s) bufA[s][t] = fmaxf(acc[s] + bb, 0.f);
  }
  __syncthreads();

  // ---- layer 4: [16 x 256] @ [256 x 1] -> out ----
  {
    const float* w4 = W4 + e * H3;
    const int lane = t & 63;
    const int sl = (t >> 6) * 4 + (lane >> 4);  // sample 0..15
    const int j = lane & 15;
    float p = 0.f;
    #pragma unroll
    for (int m = 0; m < H3 / 16; ++m)
      p = fmaf(bufA[sl][j + m * 16], w4[j + m * 16], p);
    p += __shfl_xor(p, 1);
    p += __shfl_xor(p, 2);
    p += __shfl_xor(p, 4);
    p += __shfl_xor(p, 8);
    if (j == 0 && sl < cnt) out[sidx[sl]] = p + b4[e];
  }
}

extern "C" void kernel_launch(void* const* d_in, const int* in_sizes, int n_in,
                              void* d_out, int out_size, void* d_ws, size_t ws_size,
                              hipStream_t stream) {
  const float* features = (const float*)d_in[0];
  const int*   midx     = (const int*)d_in[1];
  const float* W1 = (const float*)d_in[2];
  const float* b1 = (const float*)d_in[3];
  const float* W2 = (const float*)d_in[4];
  const float* b2 = (const float*)d_in[5];
  const float* W3 = (const float*)d_in[6];
  const float* b3 = (const float*)d_in[7];
  const float* W4 = (const float*)d_in[8];
  const float* b4 = (const float*)d_in[9];
  int*   ws  = (int*)d_ws;
  float* out = (float*)d_out;

  k_zero<<<1, 128, 0, stream>>>(ws);
  k_hist<<<NB / 256, 256, 0, stream>>>(midx, ws);
  k_plan<<<1, 64, 0, stream>>>(ws);
  k_scatter<<<NB / 256, 256, 0, stream>>>(midx, ws);
  k_mlp<<<MAXT, 256, 0, stream>>>(features, W1, b1, W2, b2, W3, b3, W4, b4, ws, out);
}

// Round 2
// 198.589 us; speedup vs baseline: 2.0754x; 2.0754x over previous
//
#include <hip/hip_runtime.h>

#define NE 24
#define NB 8192
#define FIN 15
#define H1 512
#define H2 512
#define H3 256
#define TS 32
#define SLOTS 85
#define GRIDM (8 * SLOTS)  // 680 blocks, idle ones exit

// ---- ws layout ----
// int region (int32 offsets):
#define WS_COUNT 0     // [24]
#define WS_OFF   32    // [25]
#define WS_CUR   64    // [24]
#define WS_XN    96    // [8]   tiles per XCD
#define WS_XT    128   // [8*85] packed (e<<16)|tile
#define WS_ORD   1024  // [8192]
// bf16 region starts at byte 65536:
#define WB_BYTE  65536
#define OW1 0          // [24][4][512][8]   = 393216
#define OW2 393216     // [24][64][512][8]  = 6291456
#define OW3 6684672    // [24][64][256][8]  = 3145728
#define OW4 9830400    // [24][256]         = 6144

typedef __attribute__((ext_vector_type(8))) short short8v;
typedef __attribute__((ext_vector_type(4))) float f32x4;

__device__ __forceinline__ unsigned short f2bf(float x) {
  unsigned int u = __float_as_uint(x);
  unsigned int r = (u + 0x7fffu + ((u >> 16) & 1u)) >> 16;
  return (unsigned short)r;
}
__device__ __forceinline__ float bf2f(unsigned short h) {
  return __uint_as_float(((unsigned int)h) << 16);
}

__global__ void k_zero(int* __restrict__ ws) { ws[threadIdx.x] = 0; }

__global__ void k_hist(const int* __restrict__ idx, int* __restrict__ ws) {
  int i = blockIdx.x * 256 + threadIdx.x;
  atomicAdd(&ws[WS_COUNT + idx[i]], 1);
}

__global__ void k_plan(int* __restrict__ ws) {
  if (threadIdx.x != 0) return;
  int off = 0;
  int xn[8];
  for (int x = 0; x < 8; ++x) xn[x] = 0;
  for (int e = 0; e < NE; ++e) {
    ws[WS_OFF + e] = off;
    ws[WS_CUR + e] = off;
    off += ws[WS_COUNT + e];
  }
  ws[WS_OFF + NE] = off;
  for (int e = 0; e < NE; ++e) {
    int nt = (ws[WS_COUNT + e] + TS - 1) / TS;
    for (int k = 0; k < nt; ++k) {
      int x = e & 7;
      while (xn[x] >= SLOTS) x = (x + 1) & 7;  // overflow spill (never in practice)
      ws[WS_XT + x * SLOTS + xn[x]] = (e << 16) | k;
      xn[x]++;
    }
  }
  for (int x = 0; x < 8; ++x) ws[WS_XN + x] = xn[x];
}

__global__ void k_scatter(const int* __restrict__ idx, int* __restrict__ ws) {
  int i = blockIdx.x * 256 + threadIdx.x;
  int e = idx[i];
  int p = atomicAdd(&ws[WS_CUR + e], 1);
  ws[WS_ORD + p] = i;
}

// Pack fp32 [E][KR][N] -> bf16 [E][Kb][N][8] (k = kb*8+j, zero-padded past KR).
// Segments: W1 (Kb=4,N=512,KR=15), W2 (64,512,512), W3 (64,256,512), W4 (32,1,256).
__global__ void k_pack(const float* __restrict__ W1, const float* __restrict__ W2,
                       const float* __restrict__ W3, const float* __restrict__ W4,
                       unsigned short* __restrict__ wb) {
  int g = blockIdx.x * 256 + threadIdx.x;
  const float* src;
  unsigned short* dst;
  int Kb, N, KR;
  if (g < 49152) {
    src = W1; dst = wb + OW1; Kb = 4; N = 512; KR = 15;
  } else if (g < 49152 + 786432) {
    g -= 49152; src = W2; dst = wb + OW2; Kb = 64; N = 512; KR = 512;
  } else if (g < 49152 + 786432 + 393216) {
    g -= 49152 + 786432; src = W3; dst = wb + OW3; Kb = 64; N = 256; KR = 512;
  } else {
    g -= 49152 + 786432 + 393216; src = W4; dst = wb + OW4; Kb = 32; N = 1; KR = 256;
  }
  int e = g / (Kb * N);
  int r = g % (Kb * N);
  int kb = r / N;
  int n = r % N;
  short8v v;
  #pragma unroll
  for (int j = 0; j < 8; ++j) {
    int k = kb * 8 + j;
    float f = (k < KR) ? src[((size_t)e * KR + k) * N + n] : 0.f;
    v[j] = (short)f2bf(f);
  }
  *(short8v*)(dst + (size_t)g * 8) = v;
}

// Generic MFMA layer: A acts in LDS [KS*4][32][8], B weights global [KS*4][N][8],
// fp32 bias, relu, bf16 output to LDS [N/8][32][8].
template <int NT, int KS>
__device__ __forceinline__ void layer_gemm(const unsigned short* __restrict__ aLDS,
                                           const unsigned short* __restrict__ bGlob,
                                           const float* __restrict__ bias,
                                           unsigned short* __restrict__ dLDS,
                                           int N, int ncol0, int lr, int lc) {
  f32x4 acc[2][NT];
  #pragma unroll
  for (int mt = 0; mt < 2; ++mt)
    #pragma unroll
    for (int nt = 0; nt < NT; ++nt) acc[mt][nt] = (f32x4){0.f, 0.f, 0.f, 0.f};

  for (int ks = 0; ks < KS; ++ks) {
    const unsigned short* ap = aLDS + (((ks * 4 + lc) * 32) + lr) * 8;
    short8v a0 = *(const short8v*)ap;
    short8v a1 = *(const short8v*)(ap + 16 * 8);
    const unsigned short* bp = bGlob + ((size_t)(ks * 4 + lc) * N + ncol0 + lr) * 8;
    #pragma unroll
    for (int nt = 0; nt < NT; ++nt) {
      short8v b = *(const short8v*)(bp + nt * 16 * 8);
      acc[0][nt] = __builtin_amdgcn_mfma_f32_16x16x32_bf16(a0, b, acc[0][nt], 0, 0, 0);
      acc[1][nt] = __builtin_amdgcn_mfma_f32_16x16x32_bf16(a1, b, acc[1][nt], 0, 0, 0);
    }
  }
  #pragma unroll
  for (int nt = 0; nt < NT; ++nt) {
    int col = ncol0 + nt * 16 + lr;
    float bb = bias[col];
    #pragma unroll
    for (int mt = 0; mt < 2; ++mt) {
      #pragma unroll
      for (int j = 0; j < 4; ++j) {
        int row = mt * 16 + lc * 4 + j;
        float v = fmaxf(acc[mt][nt][j] + bb, 0.f);
        dLDS[(((col >> 3) * 32) + row) * 8 + (col & 7)] = f2bf(v);
      }
    }
  }
}

__global__ __launch_bounds__(256) void k_mlp(
    const float* __restrict__ features,
    const float* __restrict__ b1, const float* __restrict__ b2,
    const float* __restrict__ b3, const float* __restrict__ b4,
    const int* __restrict__ ws, const unsigned short* __restrict__ wb,
    float* __restrict__ out) {
  __shared__ int sidx[TS];
  __shared__ __align__(16) unsigned short fA[4][TS][8];     // 2 KB
  __shared__ __align__(16) unsigned short actA[64][TS][8];  // 32 KB
  __shared__ __align__(16) unsigned short actB[64][TS][8];  // 32 KB

  const int t = threadIdx.x;
  const int wv = t >> 6;
  const int ln = t & 63;
  const int lr = ln & 15;
  const int lc = ln >> 4;

  const int bid = blockIdx.x;
  const int xcd = bid & 7;
  const int slot = bid >> 3;
  if (slot >= ws[WS_XN + xcd]) return;  // block-uniform
  const int packed = ws[WS_XT + xcd * SLOTS + slot];
  const int e = packed >> 16;
  const int tt = packed & 0xffff;
  const int start = ws[WS_OFF + e] + tt * TS;
  const int cnt = min(TS, ws[WS_OFF + e + 1] - start);

  if (t < TS) sidx[t] = (t < cnt) ? ws[WS_ORD + start + t] : ws[WS_ORD + start];
  __syncthreads();

  if (t < 128) {  // stage features as A-fragments (K padded to 32)
    int m = t >> 2, cb = t & 3;
    #pragma unroll
    for (int j = 0; j < 8; ++j) {
      int k = cb * 8 + j;
      fA[cb][m][j] = (k < FIN) ? f2bf(features[(size_t)sidx[m] * FIN + k]) : 0;
    }
  }
  __syncthreads();

  const unsigned short* w1p = wb + OW1 + (size_t)e * 4 * 512 * 8;
  const unsigned short* w2p = wb + OW2 + (size_t)e * 64 * 512 * 8;
  const unsigned short* w3p = wb + OW3 + (size_t)e * 64 * 256 * 8;
  const unsigned short* w4p = wb + OW4 + (size_t)e * 256;

  layer_gemm<8, 1>(&fA[0][0][0], w1p, b1 + e * H1, &actA[0][0][0], 512, wv * 128, lr, lc);
  __syncthreads();
  layer_gemm<8, 16>(&actA[0][0][0], w2p, b2 + e * H2, &actB[0][0][0], 512, wv * 128, lr, lc);
  __syncthreads();
  layer_gemm<4, 16>(&actB[0][0][0], w3p, b3 + e * H3, &actA[0][0][0], 256, wv * 64, lr, lc);
  __syncthreads();

  // layer 4: out[m] = h3[m][:] . W4 + b4, 8 threads per sample
  {
    int m = t >> 3, c = t & 7;
    float p = 0.f;
    #pragma unroll
    for (int kk = 0; kk < 32; ++kk) {
      int k = kk * 8 + c;  // wave reads 128B contiguous per kk: conflict-free
      p += bf2f(actA[0][0][(kk * 32 + m) * 8 + c]) * bf2f(w4p[k]);
    }
    p += __shfl_xor(p, 1);
    p += __shfl_xor(p, 2);
    p += __shfl_xor(p, 4);
    if (c == 0 && m < cnt) out[sidx[m]] = p + b4[e];
  }
}

extern "C" void kernel_launch(void* const* d_in, const int* in_sizes, int n_in,
                              void* d_out, int out_size, void* d_ws, size_t ws_size,
                              hipStream_t stream) {
  const float* features = (const float*)d_in[0];
  const int* midx = (const int*)d_in[1];
  const float* W1 = (const float*)d_in[2];
  const float* b1 = (const float*)d_in[3];
  const float* W2 = (const float*)d_in[4];
  const float* b2 = (const float*)d_in[5];
  const float* W3 = (const float*)d_in[6];
  const float* b3 = (const float*)d_in[7];
  const float* W4 = (const float*)d_in[8];
  const float* b4 = (const float*)d_in[9];
  int* ws = (int*)d_ws;
  unsigned short* wb = (unsigned short*)((char*)d_ws + WB_BYTE);
  float* out = (float*)d_out;

  k_zero<<<1, 128, 0, stream>>>(ws);
  k_hist<<<NB / 256, 256, 0, stream>>>(midx, ws);
  k_plan<<<1, 64, 0, stream>>>(ws);
  k_scatter<<<NB / 256, 256, 0, stream>>>(midx, ws);
  k_pack<<<4803, 256, 0, stream>>>(W1, W2, W3, W4, wb);
  k_mlp<<<GRIDM, 256, 0, stream>>>(features, b1, b2, b3, b4, ws, wb, out);
}

// Round 4
// 130.349 us; speedup vs baseline: 3.1620x; 1.5235x over previous
//
#include <hip/hip_runtime.h>

#define NE 24
#define NB 8192
#define FIN 15
#define H1 512
#define H2 512
#define H3 256
#define TS 32
#define SLOTS 260            // worst-case tiles per XCD (all samples on one XCD's experts)
#define GRIDM (8 * SLOTS)    // 2080 blocks, idle ones exit immediately

// ---- ws layout ----
// int region (int32 offsets):
#define WS_OFF 0      // [25]  exclusive prefix of per-expert counts
#define WS_XN  32     // [8]   tiles per XCD
#define WS_XT  64     // [8*260] packed (e<<16)|tile
#define WS_ORD 4096   // [8192] sample ids grouped by expert
// bf16 region starts at byte 65536:
#define WB_BYTE 65536
#define OW1 0         // [24][4][512][8]
#define OW2 393216    // [24][64][512][8]
#define OW3 6684672   // [24][64][256][8]
#define OW4 9830400   // [24][256]

typedef __attribute__((ext_vector_type(8))) short short8v;
typedef __attribute__((ext_vector_type(4))) float f32x4;

__device__ __forceinline__ unsigned short f2bf(float x) {
  unsigned int u = __float_as_uint(x);
  unsigned int r = (u + 0x7fffu + ((u >> 16) & 1u)) >> 16;
  return (unsigned short)r;
}
__device__ __forceinline__ float bf2f(unsigned short h) {
  return __uint_as_float(((unsigned int)h) << 16);
}

// ---- single-block planner: hist + prefix + XCD tile table + scatter ----
__global__ __launch_bounds__(1024) void k_plan2(const int* __restrict__ midx,
                                                int* __restrict__ ws) {
  __shared__ int hist[NE];
  __shared__ int off[NE + 1];
  __shared__ int cur[NE];
  __shared__ int tb[NE];   // tile slot base within the expert's XCD
  __shared__ int xn[8];
  const int t = threadIdx.x;
  if (t < NE) hist[t] = 0;
  __syncthreads();
  int ev[8];
  #pragma unroll
  for (int r = 0; r < 8; ++r) {
    ev[r] = midx[r * 1024 + t];
    atomicAdd(&hist[ev[r]], 1);
  }
  __syncthreads();
  if (t == 0) {
    int o = 0;
    #pragma unroll
    for (int i = 0; i < NE; ++i) { off[i] = o; cur[i] = o; o += hist[i]; }
    off[NE] = o;
  }
  if (t >= 32 && t < 40) {   // per-XCD tile-slot prefix (no scratch: strided loop)
    const int x = t - 32;
    int o = 0;
    for (int i = x; i < NE; i += 8) { tb[i] = o; o += (hist[i] + TS - 1) / TS; }
    xn[x] = o;
  }
  __syncthreads();
  if (t < NE + 1) ws[WS_OFF + t] = off[t];
  if (t >= 32 && t < 40) ws[WS_XN + t - 32] = xn[t - 32];
  for (int e = 0; e < NE; ++e) {
    const int nt = (hist[e] + TS - 1) / TS;
    for (int k = t; k < nt; k += 1024)
      ws[WS_XT + (e & 7) * SLOTS + tb[e] + k] = (e << 16) | k;
  }
  #pragma unroll
  for (int r = 0; r < 8; ++r) {
    const int p = atomicAdd(&cur[ev[r]], 1);
    ws[WS_ORD + p] = r * 1024 + t;
  }
}

// Pack fp32 [E][KR][N] -> bf16 [E][Kb][N][8] (k = kb*8+j, zero-padded past KR).
__global__ void k_pack(const float* __restrict__ W1, const float* __restrict__ W2,
                       const float* __restrict__ W3, const float* __restrict__ W4,
                       unsigned short* __restrict__ wb) {
  int g = blockIdx.x * 256 + threadIdx.x;
  const float* src;
  unsigned short* dst;
  int Kb, N, KR;
  if (g < 49152) {
    src = W1; dst = wb + OW1; Kb = 4; N = 512; KR = 15;
  } else if (g < 49152 + 786432) {
    g -= 49152; src = W2; dst = wb + OW2; Kb = 64; N = 512; KR = 512;
  } else if (g < 49152 + 786432 + 393216) {
    g -= 49152 + 786432; src = W3; dst = wb + OW3; Kb = 64; N = 256; KR = 512;
  } else {
    g -= 49152 + 786432 + 393216; src = W4; dst = wb + OW4; Kb = 32; N = 1; KR = 256;
  }
  int e = g / (Kb * N);
  int r = g % (Kb * N);
  int kb = r / N;
  int n = r % N;
  short8v v;
  #pragma unroll
  for (int j = 0; j < 8; ++j) {
    int k = kb * 8 + j;
    float f = (k < KR) ? src[((size_t)e * KR + k) * N + n] : 0.f;
    v[j] = (short)f2bf(f);
  }
  *(short8v*)(dst + (size_t)g * 8) = v;
}

// MFMA layer with depth-1 B prefetch. A in LDS [KS*4][32][8], B global
// [KS*4][N][8], fp32 bias, relu, bf16 out to LDS [N/8][32][8].
template <int NT, int KS>
__device__ __forceinline__ void layer_gemm(const unsigned short* __restrict__ aLDS,
                                           const unsigned short* __restrict__ bGlob,
                                           const float* __restrict__ bias,
                                           unsigned short* __restrict__ dLDS,
                                           int N, int ncol0, int lr, int lc) {
  f32x4 acc[2][NT];
  #pragma unroll
  for (int mt = 0; mt < 2; ++mt)
    #pragma unroll
    for (int nt = 0; nt < NT; ++nt) acc[mt][nt] = (f32x4){0.f, 0.f, 0.f, 0.f};

  short8v bcur[NT], bnxt[NT];
  {
    const unsigned short* bp = bGlob + ((size_t)lc * N + ncol0 + lr) * 8;
    #pragma unroll
    for (int nt = 0; nt < NT; ++nt) bcur[nt] = *(const short8v*)(bp + nt * 16 * 8);
  }
  #pragma unroll
  for (int ks = 0; ks < KS; ++ks) {
    if (ks + 1 < KS) {
      const unsigned short* bq =
          bGlob + ((size_t)((ks + 1) * 4 + lc) * N + ncol0 + lr) * 8;
      #pragma unroll
      for (int nt = 0; nt < NT; ++nt) bnxt[nt] = *(const short8v*)(bq + nt * 16 * 8);
    }
    const unsigned short* ap = aLDS + (((ks * 4 + lc) * 32) + lr) * 8;
    short8v a0 = *(const short8v*)ap;
    short8v a1 = *(const short8v*)(ap + 128);
    #pragma unroll
    for (int nt = 0; nt < NT; ++nt) {
      acc[0][nt] = __builtin_amdgcn_mfma_f32_16x16x32_bf16(a0, bcur[nt], acc[0][nt], 0, 0, 0);
      acc[1][nt] = __builtin_amdgcn_mfma_f32_16x16x32_bf16(a1, bcur[nt], acc[1][nt], 0, 0, 0);
    }
    #pragma unroll
    for (int nt = 0; nt < NT; ++nt) bcur[nt] = bnxt[nt];
  }
  #pragma unroll
  for (int nt = 0; nt < NT; ++nt) {
    const int col = ncol0 + nt * 16 + lr;
    const float bb = bias[col];
    #pragma unroll
    for (int mt = 0; mt < 2; ++mt) {
      #pragma unroll
      for (int j = 0; j < 4; ++j) {
        const int row = mt * 16 + lc * 4 + j;
        const float v = fmaxf(acc[mt][nt][j] + bb, 0.f);
        dLDS[(((col >> 3) * 32) + row) * 8 + (col & 7)] = f2bf(v);
      }
    }
  }
}

__global__ __launch_bounds__(512) void k_mlp(
    const float* __restrict__ features,
    const float* __restrict__ b1, const float* __restrict__ b2,
    const float* __restrict__ b3, const float* __restrict__ b4,
    const int* __restrict__ ws, const unsigned short* __restrict__ wb,
    float* __restrict__ out) {
  __shared__ int sidx[TS];
  __shared__ __align__(16) unsigned short fA[4][TS][8];     // 2 KB
  __shared__ __align__(16) unsigned short actA[64][TS][8];  // 32 KB
  __shared__ __align__(16) unsigned short actB[64][TS][8];  // 32 KB

  const int t = threadIdx.x;
  const int wv = t >> 6;   // 0..7
  const int ln = t & 63;
  const int lr = ln & 15;
  const int lc = ln >> 4;

  const int bid = blockIdx.x;
  const int xcd = bid & 7;
  const int slot = bid >> 3;
  if (slot >= ws[WS_XN + xcd]) return;  // block-uniform
  const int packed = ws[WS_XT + xcd * SLOTS + slot];
  const int e = packed >> 16;
  const int tt = packed & 0xffff;
  const int start = ws[WS_OFF + e] + tt * TS;
  const int cnt = min(TS, ws[WS_OFF + e + 1] - start);

  if (t < TS) sidx[t] = (t < cnt) ? ws[WS_ORD + start + t] : ws[WS_ORD + start];
  __syncthreads();

  if (t < 128) {  // stage features as A-fragments (K padded to 32)
    int m = t >> 2, cb = t & 3;
    #pragma unroll
    for (int j = 0; j < 8; ++j) {
      int k = cb * 8 + j;
      fA[cb][m][j] = (k < FIN) ? f2bf(features[(size_t)sidx[m] * FIN + k]) : 0;
    }
  }
  __syncthreads();

  const unsigned short* w1p = wb + OW1 + (size_t)e * 4 * 512 * 8;
  const unsigned short* w2p = wb + OW2 + (size_t)e * 64 * 512 * 8;
  const unsigned short* w3p = wb + OW3 + (size_t)e * 64 * 256 * 8;
  const unsigned short* w4p = wb + OW4 + (size_t)e * 256;

  layer_gemm<4, 1>(&fA[0][0][0], w1p, b1 + e * H1, &actA[0][0][0], 512, wv * 64, lr, lc);
  __syncthreads();
  layer_gemm<4, 16>(&actA[0][0][0], w2p, b2 + e * H2, &actB[0][0][0], 512, wv * 64, lr, lc);
  __syncthreads();
  layer_gemm<2, 16>(&actB[0][0][0], w3p, b3 + e * H3, &actA[0][0][0], 256, wv * 32, lr, lc);
  __syncthreads();

  // layer 4: out[m] = h3[m][:] . W4 + b4, 8 threads per sample (first 256 thr)
  if (t < 256) {
    int m = t >> 3, c = t & 7;
    float p = 0.f;
    #pragma unroll
    for (int kk = 0; kk < 32; ++kk)
      p += bf2f(actA[0][0][(kk * 32 + m) * 8 + c]) * bf2f(w4p[kk * 8 + c]);
    p += __shfl_xor(p, 1);
    p += __shfl_xor(p, 2);
    p += __shfl_xor(p, 4);
    if (c == 0 && m < cnt) out[sidx[m]] = p + b4[e];
  }
}

extern "C" void kernel_launch(void* const* d_in, const int* in_sizes, int n_in,
                              void* d_out, int out_size, void* d_ws, size_t ws_size,
                              hipStream_t stream) {
  const float* features = (const float*)d_in[0];
  const int* midx = (const int*)d_in[1];
  const float* W1 = (const float*)d_in[2];
  const float* b1 = (const float*)d_in[3];
  const float* W2 = (const float*)d_in[4];
  const float* b2 = (const float*)d_in[5];
  const float* W3 = (const float*)d_in[6];
  const float* b3 = (const float*)d_in[7];
  const float* W4 = (const float*)d_in[8];
  const float* b4 = (const float*)d_in[9];
  int* ws = (int*)d_ws;
  unsigned short* wb = (unsigned short*)((char*)d_ws + WB_BYTE);
  float* out = (float*)d_out;

  k_pack<<<4803, 256, 0, stream>>>(W1, W2, W3, W4, wb);
  k_plan2<<<1, 1024, 0, stream>>>(midx, ws);
  k_mlp<<<GRIDM, 512, 0, stream>>>(features, b1, b2, b3, b4, ws, wb, out);
}

// Round 5
// 128.575 us; speedup vs baseline: 3.2056x; 1.0138x over previous
//
#include <hip/hip_runtime.h>

#define NE 24
#define NB 8192
#define FIN 15
#define H1 512
#define H2 512
#define H3 256
#define TS 32
#define SLOTS 260            // worst-case tiles per XCD
#define GRIDM (8 * SLOTS)    // 2080 blocks, idle ones exit immediately
#define PACKBLK 4803         // pack blocks; block PACKBLK does planning

// ---- ws layout ----
// int region (int32 offsets):
#define WS_OFF 0      // [25]  exclusive prefix of per-expert counts
#define WS_XN  32     // [8]   tiles per XCD
#define WS_XT  64     // [8*260] packed (e<<16)|tile
#define WS_ORD 4096   // [8192] sample ids grouped by expert
// bf16 region starts at byte 65536:
#define WB_BYTE 65536
#define OW1 0         // [24][4][512][8]
#define OW2 393216    // [24][64][512][8]
#define OW3 6684672   // [24][64][256][8]
#define OW4 9830400   // [24][256]

typedef __attribute__((ext_vector_type(8))) short short8v;
typedef __attribute__((ext_vector_type(4))) float f32x4;

__device__ __forceinline__ unsigned short f2bf(float x) {
  unsigned int u = __float_as_uint(x);
  unsigned int r = (u + 0x7fffu + ((u >> 16) & 1u)) >> 16;
  return (unsigned short)r;
}
__device__ __forceinline__ float bf2f(unsigned short h) {
  return __uint_as_float(((unsigned int)h) << 16);
}

// ---- fused pack + plan ----
// Blocks [0, PACKBLK): pack fp32 [E][KR][N] -> bf16 [E][Kb][N][8].
// Block PACKBLK: histogram/prefix/XCD-tile-table/scatter (256 threads).
__global__ __launch_bounds__(256) void k_pack(
    const float* __restrict__ W1, const float* __restrict__ W2,
    const float* __restrict__ W3, const float* __restrict__ W4,
    const int* __restrict__ midx, int* __restrict__ ws,
    unsigned short* __restrict__ wb) {
  const int t = threadIdx.x;
  if (blockIdx.x == PACKBLK) {
    __shared__ int hist[NE];
    __shared__ int off[NE + 1];
    __shared__ int cur[NE];
    __shared__ int tb[NE];
    __shared__ int xn[8];
    if (t < NE) hist[t] = 0;
    __syncthreads();
    int ev[32];
    #pragma unroll
    for (int r = 0; r < 32; ++r) {
      ev[r] = midx[r * 256 + t];
      atomicAdd(&hist[ev[r]], 1);
    }
    __syncthreads();
    if (t == 0) {
      int o = 0;
      #pragma unroll
      for (int i = 0; i < NE; ++i) { off[i] = o; cur[i] = o; o += hist[i]; }
      off[NE] = o;
    }
    if (t >= 32 && t < 40) {  // per-XCD tile-slot prefix, strided (no scratch)
      const int x = t - 32;
      int o = 0;
      for (int i = x; i < NE; i += 8) { tb[i] = o; o += (hist[i] + TS - 1) / TS; }
      xn[x] = o;
    }
    __syncthreads();
    if (t < NE + 1) ws[WS_OFF + t] = off[t];
    if (t >= 32 && t < 40) ws[WS_XN + t - 32] = xn[t - 32];
    for (int e = 0; e < NE; ++e) {
      const int nt = (hist[e] + TS - 1) / TS;
      for (int k = t; k < nt; k += 256)
        ws[WS_XT + (e & 7) * SLOTS + tb[e] + k] = (e << 16) | k;
    }
    #pragma unroll
    for (int r = 0; r < 32; ++r) {
      const int p = atomicAdd(&cur[ev[r]], 1);
      ws[WS_ORD + p] = r * 256 + t;
    }
    return;
  }
  int g = blockIdx.x * 256 + t;
  const float* src;
  unsigned short* dst;
  int Kb, N, KR;
  if (g < 49152) {
    src = W1; dst = wb + OW1; Kb = 4; N = 512; KR = 15;
  } else if (g < 49152 + 786432) {
    g -= 49152; src = W2; dst = wb + OW2; Kb = 64; N = 512; KR = 512;
  } else if (g < 49152 + 786432 + 393216) {
    g -= 49152 + 786432; src = W3; dst = wb + OW3; Kb = 64; N = 256; KR = 512;
  } else {
    g -= 49152 + 786432 + 393216; src = W4; dst = wb + OW4; Kb = 32; N = 1; KR = 256;
  }
  int e = g / (Kb * N);
  int r = g % (Kb * N);
  int kb = r / N;
  int n = r % N;
  short8v v;
  #pragma unroll
  for (int j = 0; j < 8; ++j) {
    int k = kb * 8 + j;
    float f = (k < KR) ? src[((size_t)e * KR + k) * N + n] : 0.f;
    v[j] = (short)f2bf(f);
  }
  *(short8v*)(dst + (size_t)g * 8) = v;
}

// MFMA layer with depth-3 rotating B prefetch (all buffer indices are
// compile-time: the ks loop is fully unrolled, so bb[(ks+3)&3] is static).
// A in LDS [KS*4][32][8], B global [KS*4][N][8], fp32 bias, relu,
// bf16 out to LDS [N/8][32][8].
template <int NT, int KS>
__device__ __forceinline__ void layer_gemm(const unsigned short* __restrict__ aLDS,
                                           const unsigned short* __restrict__ bGlob,
                                           const float* __restrict__ bias,
                                           unsigned short* __restrict__ dLDS,
                                           int N, int ncol0, int lr, int lc) {
  f32x4 acc[2][NT];
  #pragma unroll
  for (int mt = 0; mt < 2; ++mt)
    #pragma unroll
    for (int nt = 0; nt < NT; ++nt) acc[mt][nt] = (f32x4){0.f, 0.f, 0.f, 0.f};

  const unsigned short* bbase = bGlob + ((size_t)lc * N + ncol0 + lr) * 8;
  const size_t kstep = (size_t)4 * N * 8;  // one ks slice = 4 k-rows

  short8v bb[4][NT];
  #pragma unroll
  for (int p = 0; p < 3; ++p) {
    if (p < KS) {
      #pragma unroll
      for (int nt = 0; nt < NT; ++nt)
        bb[p][nt] = *(const short8v*)(bbase + p * kstep + nt * 128);
    }
  }
  #pragma unroll
  for (int ks = 0; ks < KS; ++ks) {
    if (ks + 3 < KS) {
      #pragma unroll
      for (int nt = 0; nt < NT; ++nt)
        bb[(ks + 3) & 3][nt] = *(const short8v*)(bbase + (ks + 3) * kstep + nt * 128);
    }
    const unsigned short* ap = aLDS + (((ks * 4 + lc) * 32) + lr) * 8;
    short8v a0 = *(const short8v*)ap;
    short8v a1 = *(const short8v*)(ap + 128);
    #pragma unroll
    for (int nt = 0; nt < NT; ++nt) {
      acc[0][nt] = __builtin_amdgcn_mfma_f32_16x16x32_bf16(a0, bb[ks & 3][nt], acc[0][nt], 0, 0, 0);
      acc[1][nt] = __builtin_amdgcn_mfma_f32_16x16x32_bf16(a1, bb[ks & 3][nt], acc[1][nt], 0, 0, 0);
    }
  }
  #pragma unroll
  for (int nt = 0; nt < NT; ++nt) {
    const int col = ncol0 + nt * 16 + lr;
    const float bb2 = bias[col];
    #pragma unroll
    for (int mt = 0; mt < 2; ++mt) {
      #pragma unroll
      for (int j = 0; j < 4; ++j) {
        const int row = mt * 16 + lc * 4 + j;
        const float v = fmaxf(acc[mt][nt][j] + bb2, 0.f);
        dLDS[(((col >> 3) * 32) + row) * 8 + (col & 7)] = f2bf(v);
      }
    }
  }
}

__global__ __launch_bounds__(512) void k_mlp(
    const float* __restrict__ features,
    const float* __restrict__ b1, const float* __restrict__ b2,
    const float* __restrict__ b3, const float* __restrict__ b4,
    const int* __restrict__ ws, const unsigned short* __restrict__ wb,
    float* __restrict__ out) {
  __shared__ int sidx[TS];
  __shared__ __align__(16) unsigned short fA[4][TS][8];     // 2 KB
  __shared__ __align__(16) unsigned short actA[64][TS][8];  // 32 KB
  __shared__ __align__(16) unsigned short actB[64][TS][8];  // 32 KB

  const int t = threadIdx.x;
  const int wv = t >> 6;   // 0..7
  const int ln = t & 63;
  const int lr = ln & 15;
  const int lc = ln >> 4;

  const int bid = blockIdx.x;
  const int xcd = bid & 7;
  const int slot = bid >> 3;
  if (slot >= ws[WS_XN + xcd]) return;  // block-uniform
  const int packed = ws[WS_XT + xcd * SLOTS + slot];
  const int e = packed >> 16;
  const int tt = packed & 0xffff;
  const int start = ws[WS_OFF + e] + tt * TS;
  const int cnt = min(TS, ws[WS_OFF + e + 1] - start);

  if (t < TS) sidx[t] = (t < cnt) ? ws[WS_ORD + start + t] : ws[WS_ORD + start];
  __syncthreads();

  if (t < 128) {  // stage features as A-fragments (K padded to 32)
    int m = t >> 2, cb = t & 3;
    #pragma unroll
    for (int j = 0; j < 8; ++j) {
      int k = cb * 8 + j;
      fA[cb][m][j] = (k < FIN) ? f2bf(features[(size_t)sidx[m] * FIN + k]) : 0;
    }
  }
  __syncthreads();

  const unsigned short* w1p = wb + OW1 + (size_t)e * 4 * 512 * 8;
  const unsigned short* w2p = wb + OW2 + (size_t)e * 64 * 512 * 8;
  const unsigned short* w3p = wb + OW3 + (size_t)e * 64 * 256 * 8;
  const unsigned short* w4p = wb + OW4 + (size_t)e * 256;

  layer_gemm<4, 1>(&fA[0][0][0], w1p, b1 + e * H1, &actA[0][0][0], 512, wv * 64, lr, lc);
  __syncthreads();
  layer_gemm<4, 16>(&actA[0][0][0], w2p, b2 + e * H2, &actB[0][0][0], 512, wv * 64, lr, lc);
  __syncthreads();
  layer_gemm<2, 16>(&actB[0][0][0], w3p, b3 + e * H3, &actA[0][0][0], 256, wv * 32, lr, lc);
  __syncthreads();

  // layer 4: out[m] = h3[m][:] . W4 + b4, 8 threads per sample (first 256 thr)
  if (t < 256) {
    int m = t >> 3, c = t & 7;
    float p = 0.f;
    #pragma unroll
    for (int kk = 0; kk < 32; ++kk)
      p += bf2f(actA[0][0][(kk * 32 + m) * 8 + c]) * bf2f(w4p[kk * 8 + c]);
    p += __shfl_xor(p, 1);
    p += __shfl_xor(p, 2);
    p += __shfl_xor(p, 4);
    if (c == 0 && m < cnt) out[sidx[m]] = p + b4[e];
  }
}

extern "C" void kernel_launch(void* const* d_in, const int* in_sizes, int n_in,
                              void* d_out, int out_size, void* d_ws, size_t ws_size,
                              hipStream_t stream) {
  const float* features = (const float*)d_in[0];
  const int* midx = (const int*)d_in[1];
  const float* W1 = (const float*)d_in[2];
  const float* b1 = (const float*)d_in[3];
  const float* W2 = (const float*)d_in[4];
  const float* b2 = (const float*)d_in[5];
  const float* W3 = (const float*)d_in[6];
  const float* b3 = (const float*)d_in[7];
  const float* W4 = (const float*)d_in[8];
  const float* b4 = (const float*)d_in[9];
  int* ws = (int*)d_ws;
  unsigned short* wb = (unsigned short*)((char*)d_ws + WB_BYTE);
  float* out = (float*)d_out;

  k_pack<<<PACKBLK + 1, 256, 0, stream>>>(W1, W2, W3, W4, midx, ws, wb);
  k_mlp<<<GRIDM, 512, 0, stream>>>(features, b1, b2, b3, b4, ws, wb, out);
}